// Round 1
// baseline (1360.713 us; speedup 1.0000x reference)
//
#include <hip/hip_runtime.h>
#include <hip/hip_bf16.h>

using bf16x8 = short __attribute__((ext_vector_type(8)));
using f32x16 = float __attribute__((ext_vector_type(16)));

#define MROWS 100352      // 2048*49
#define SCALE_Q 0.17677669529663687f

static __device__ __forceinline__ unsigned short f2bs(float f){
  unsigned u = __builtin_bit_cast(unsigned, f);
  unsigned r = (u + 0x7FFFu + ((u >> 16) & 1u)) >> 16;   // RNE
  return (unsigned short)r;
}
static __device__ __forceinline__ unsigned packbf(float a, float b){
  return (unsigned)f2bs(a) | ((unsigned)f2bs(b) << 16);
}

// ---------------- K0: weight conversion (transposed, head-permuted) + bias table ----------------
// permuted qk col c (0..511): head=c>>6, within=c&63 -> orig qkv col (c>>6)*192 + (c&63)
// permuted v row dv (0..1023): head=dv>>7 -> orig col (dv>>7)*192 + 64 + (dv&127)
__global__ void k_convert(const float* __restrict__ qkvW, const float* __restrict__ qkvB,
                          const float* __restrict__ projW, const float* __restrict__ ab,
                          short* __restrict__ WqkT, short* __restrict__ WvT, short* __restrict__ WpT,
                          float* __restrict__ bqk, float* __restrict__ bv, float* __restrict__ bias_exp){
  int i = blockIdx.x * 256 + threadIdx.x;
  if (i < 512*384){
    int c = i / 384, f = i - c*384;
    WqkT[i] = (short)f2bs(qkvW[f*1536 + (c>>6)*192 + (c&63)]);
    return;
  }
  i -= 512*384;
  if (i < 1024*384){
    int dv = i / 384, f = i - dv*384;
    WvT[i] = (short)f2bs(qkvW[f*1536 + (dv>>7)*192 + 64 + (dv&127)]);
    return;
  }
  i -= 1024*384;
  if (i < 384*1024){
    int j = i / 1024, m = i - j*1024;
    WpT[i] = (short)f2bs(projW[m*384 + j]);
    return;
  }
  i -= 384*1024;
  if (i < 512){ bqk[i] = qkvB[(i>>6)*192 + (i&63)]; return; }
  i -= 512;
  if (i < 1024){ bv[i] = qkvB[(i>>7)*192 + 64 + (i&127)]; return; }
  i -= 1024;
  if (i < 8*49*49){
    int h = i / 2401, rem = i - h*2401;
    int r = rem / 49, n = rem - r*49;
    int rh = r/7, rw = r - rh*7, ch = n/7, cw = n - ch*7;
    int dh = rh>ch ? rh-ch : ch-rh, dw = rw>cw ? rw-cw : cw-rw;
    bias_exp[(h*64 + r)*49 + n] = ab[h*49 + dh*7 + dw];
  }
}

// ---------------- K1a: qk GEMM  C[100352][512] = x @ Wqk + b  (bf16 out) ----------------
// block: 512 thr (8 waves, 2M x 4N), tile 128x256, grid (784, 2)
__global__ __launch_bounds__(512) void k_qk_gemm(const float* __restrict__ x, const short* __restrict__ WqkT,
                                                 const float* __restrict__ bqk, short* __restrict__ qkbuf){
  const int lane = threadIdx.x & 63;
  const int w = threadIdx.x >> 6;
  const int hi = lane >> 5, l31 = lane & 31;
  const int R0 = blockIdx.x*128 + (w>>2)*64;
  const int C0 = blockIdx.y*256 + (w&3)*64;
  f32x16 acc[2][2];
  #pragma unroll
  for (int mt=0; mt<2; ++mt)
    #pragma unroll
    for (int nt=0; nt<2; ++nt) acc[mt][nt] = (f32x16)0.0f;

  for (int ks=0; ks<24; ++ks){
    const int f0 = ks*16 + hi*8;
    bf16x8 aF[2], bF[2];
    #pragma unroll
    for (int mt=0; mt<2; ++mt){
      const float* pa = x + (R0 + 32*mt + l31)*384 + f0;
      float4 u0 = *reinterpret_cast<const float4*>(pa);
      float4 u1 = *reinterpret_cast<const float4*>(pa + 4);
      bf16x8 t;
      t[0]=(short)f2bs(u0.x); t[1]=(short)f2bs(u0.y); t[2]=(short)f2bs(u0.z); t[3]=(short)f2bs(u0.w);
      t[4]=(short)f2bs(u1.x); t[5]=(short)f2bs(u1.y); t[6]=(short)f2bs(u1.z); t[7]=(short)f2bs(u1.w);
      aF[mt] = t;
    }
    #pragma unroll
    for (int nt=0; nt<2; ++nt)
      bF[nt] = *reinterpret_cast<const bf16x8*>(WqkT + (C0 + 32*nt + l31)*384 + f0);
    #pragma unroll
    for (int mt=0; mt<2; ++mt)
      #pragma unroll
      for (int nt=0; nt<2; ++nt)
        acc[mt][nt] = __builtin_amdgcn_mfma_f32_32x32x16_bf16(aF[mt], bF[nt], acc[mt][nt], 0, 0, 0);
  }
  #pragma unroll
  for (int nt=0; nt<2; ++nt){
    const int c = C0 + 32*nt + l31;
    const float bb = bqk[c];
    #pragma unroll
    for (int mt=0; mt<2; ++mt)
      #pragma unroll
      for (int rg=0; rg<16; ++rg){
        const int r = R0 + 32*mt + (rg&3) + 8*(rg>>2) + 4*hi;
        qkbuf[r*512 + c] = (short)f2bs(acc[mt][nt][rg] + bb);
      }
  }
}

// ---------------- K1b: V^T GEMM  per batch: C[dv][n] = Wv^T @ x_b^T + bv  -> vT[b][1024][56] ----------------
// block: 256 thr (4 waves, 4M x 1N), tile 256x64, grid (4, 2048)
__global__ __launch_bounds__(256) void k_vt(const float* __restrict__ x, const short* __restrict__ WvT,
                                            const float* __restrict__ bv, short* __restrict__ vT){
  const int lane = threadIdx.x & 63, w = threadIdx.x >> 6;
  const int hi = lane >> 5, l31 = lane & 31;
  const int b = blockIdx.y;
  const int R0 = blockIdx.x*256 + w*64;
  f32x16 acc[2][2];
  #pragma unroll
  for (int mt=0; mt<2; ++mt)
    #pragma unroll
    for (int nt=0; nt<2; ++nt) acc[mt][nt] = (f32x16)0.0f;

  for (int ks=0; ks<24; ++ks){
    const int f0 = ks*16 + hi*8;
    bf16x8 aF[2], bF[2];
    #pragma unroll
    for (int mt=0; mt<2; ++mt)
      aF[mt] = *reinterpret_cast<const bf16x8*>(WvT + (R0 + 32*mt + l31)*384 + f0);
    #pragma unroll
    for (int nt=0; nt<2; ++nt){
      const int row = b*49 + 32*nt + l31;
      if (row < MROWS){
        const float* px = x + row*384 + f0;
        float4 u0 = *reinterpret_cast<const float4*>(px);
        float4 u1 = *reinterpret_cast<const float4*>(px + 4);
        bf16x8 t;
        t[0]=(short)f2bs(u0.x); t[1]=(short)f2bs(u0.y); t[2]=(short)f2bs(u0.z); t[3]=(short)f2bs(u0.w);
        t[4]=(short)f2bs(u1.x); t[5]=(short)f2bs(u1.y); t[6]=(short)f2bs(u1.z); t[7]=(short)f2bs(u1.w);
        bF[nt] = t;
      } else bF[nt] = (bf16x8)(short)0;
    }
    #pragma unroll
    for (int mt=0; mt<2; ++mt)
      #pragma unroll
      for (int nt=0; nt<2; ++nt)
        acc[mt][nt] = __builtin_amdgcn_mfma_f32_32x32x16_bf16(aF[mt], bF[nt], acc[mt][nt], 0, 0, 0);
  }
  #pragma unroll
  for (int mt=0; mt<2; ++mt)
    #pragma unroll
    for (int rg=0; rg<16; ++rg){
      const int dv = R0 + 32*mt + (rg&3) + 8*(rg>>2) + 4*hi;
      const float bb = bv[dv];
      const int base = (b*1024 + dv)*56;
      #pragma unroll
      for (int nt=0; nt<2; ++nt){
        const int n = 32*nt + l31;
        if (n < 49)      vT[base + n] = (short)f2bs(acc[mt][nt][rg] + bb);
        else if (n < 56) vT[base + n] = 0;   // NaN-safe pad (multiplied by P==0)
      }
    }
}

// ---------------- K2: attention per (b, h) — swapped QK^T, in-register softmax+P ----------------
// block: 512 thr (8 waves = 8 heads), grid 2048
__global__ __launch_bounds__(512) void k_attn(const short* __restrict__ qkbuf, const short* __restrict__ vT,
                                              const float* __restrict__ bias_exp, short* __restrict__ attn_out){
  const int lane = threadIdx.x & 63, h = threadIdx.x >> 6;
  const int hi = lane >> 5, l31 = lane & 31;
  const int b = blockIdx.x;

  // K fragments (A operand of S^T = K @ Q^T), hoisted across both row-blocks
  bf16x8 kf[2][2];
  #pragma unroll
  for (int mt=0; mt<2; ++mt){
    const int n = 32*mt + l31;
    #pragma unroll
    for (int ks=0; ks<2; ++ks)
      kf[mt][ks] = (n < 49)
        ? *reinterpret_cast<const bf16x8*>(qkbuf + (b*49+n)*512 + h*64 + 32 + ks*16 + hi*8)
        : (bf16x8)(short)0;
  }
  const short* vbase = vT + (b*1024 + h*128)*56;

  for (int rb=0; rb<2; ++rb){
    const int r = 32*rb + l31;   // this lane's q-row
    bf16x8 qf[2];
    #pragma unroll
    for (int ks=0; ks<2; ++ks)
      qf[ks] = (r < 49)
        ? *reinterpret_cast<const bf16x8*>(qkbuf + (b*49+r)*512 + h*64 + ks*16 + hi*8)
        : (bf16x8)(short)0;

    f32x16 s[2];
    s[0] = (f32x16)0.0f; s[1] = (f32x16)0.0f;
    #pragma unroll
    for (int ks=0; ks<2; ++ks){
      s[0] = __builtin_amdgcn_mfma_f32_32x32x16_bf16(kf[0][ks], qf[ks], s[0], 0, 0, 0);
      s[1] = __builtin_amdgcn_mfma_f32_32x32x16_bf16(kf[1][ks], qf[ks], s[1], 0, 0, 0);
    }

    // scale + bias + mask, row max (row lives in lanes l and l^32)
    float mloc = -3.0e38f;
    #pragma unroll
    for (int mt=0; mt<2; ++mt)
      #pragma unroll
      for (int rg=0; rg<16; ++rg){
        const int n = 32*mt + (rg&3) + 8*(rg>>2) + 4*hi;
        float v = s[mt][rg];
        v = (n < 49) ? v*SCALE_Q + bias_exp[(h*64 + r)*49 + n] : -1.0e30f;
        s[mt][rg] = v;
        mloc = fmaxf(mloc, v);
      }
    const float mrow = fmaxf(mloc, __shfl_xor(mloc, 32));
    float sloc = 0.0f;
    #pragma unroll
    for (int mt=0; mt<2; ++mt)
      #pragma unroll
      for (int rg=0; rg<16; ++rg){
        const float p = __expf(s[mt][rg] - mrow);
        s[mt][rg] = p; sloc += p;
      }
    const float inv = 1.0f / (sloc + __shfl_xor(sloc, 32));
    #pragma unroll
    for (int mt=0; mt<2; ++mt)
      #pragma unroll
      for (int rg=0; rg<16; ++rg) s[mt][rg] *= inv;

    // pack all 8 n-octets: pk[o] = residues (4*hi..4*hi+3) of octet o for this lane's row
    unsigned pk[8][2];
    #pragma unroll
    for (int o=0; o<8; ++o){
      const int mt = o>>2, base = 4*(o&3);
      pk[o][0] = packbf(s[mt][base+0], s[mt][base+1]);
      pk[o][1] = packbf(s[mt][base+2], s[mt][base+3]);
    }
    // A fragments for PV: lane needs full octet (2*ks + hi); other half from lane^32
    bf16x8 af[4];
    #pragma unroll
    for (int ks=0; ks<4; ++ks){
      const unsigned e0 = pk[2*ks][0],   e1 = pk[2*ks][1];
      const unsigned o0 = pk[2*ks+1][0], o1 = pk[2*ks+1][1];
      const unsigned own0 = hi ? o0 : e0, own1 = hi ? o1 : e1;
      const unsigned oth0 = hi ? e0 : o0, oth1 = hi ? e1 : o1;  // what partner needs
      const unsigned sw0 = __shfl_xor(oth0, 32), sw1 = __shfl_xor(oth1, 32);
      const unsigned lo0 = hi ? sw0 : own0, lo1 = hi ? sw1 : own1;
      const unsigned h0  = hi ? own0 : sw0, h1  = hi ? own1 : sw1;
      union { bf16x8 v; unsigned u[4]; } t;
      t.u[0]=lo0; t.u[1]=lo1; t.u[2]=h0; t.u[3]=h1;
      af[ks] = t.v;
    }

    // PV: O[r][d] = P @ V, B from vT (n-contiguous)
    f32x16 accO[4];
    #pragma unroll
    for (int dt=0; dt<4; ++dt) accO[dt] = (f32x16)0.0f;
    #pragma unroll
    for (int dt=0; dt<4; ++dt)
      #pragma unroll
      for (int ks=0; ks<4; ++ks){
        const bf16x8 bvf = *reinterpret_cast<const bf16x8*>(vbase + (l31 + 32*dt)*56 + ks*16 + hi*8);
        accO[dt] = __builtin_amdgcn_mfma_f32_32x32x16_bf16(af[ks], bvf, accO[dt], 0, 0, 0);
      }
    #pragma unroll
    for (int dt=0; dt<4; ++dt)
      #pragma unroll
      for (int rg=0; rg<16; ++rg){
        const int rr = 32*rb + (rg&3) + 8*(rg>>2) + 4*hi;
        if (rr < 49)
          attn_out[(b*49+rr)*1024 + h*128 + l31 + 32*dt] = (short)f2bs(accO[dt][rg]);
      }
  }
}

// ---------------- K3: proj GEMM  out[100352][384] = attn_out @ Wp + pb  (fp32 out) ----------------
// block: 512 thr (8 waves, 2M x 4N), tile 128x384, grid 784
__global__ __launch_bounds__(512) void k_proj(const short* __restrict__ aout, const short* __restrict__ WpT,
                                              const float* __restrict__ pb, float* __restrict__ out){
  const int lane = threadIdx.x & 63, w = threadIdx.x >> 6;
  const int hi = lane >> 5, l31 = lane & 31;
  const int R0 = blockIdx.x*128 + (w>>2)*64;
  const int C0 = (w&3)*96;
  f32x16 acc[2][3];
  #pragma unroll
  for (int mt=0; mt<2; ++mt)
    #pragma unroll
    for (int nt=0; nt<3; ++nt) acc[mt][nt] = (f32x16)0.0f;

  for (int ks=0; ks<64; ++ks){
    const int m0 = ks*16 + hi*8;
    bf16x8 aF[2], bF[3];
    #pragma unroll
    for (int mt=0; mt<2; ++mt)
      aF[mt] = *reinterpret_cast<const bf16x8*>(aout + (R0 + 32*mt + l31)*1024 + m0);
    #pragma unroll
    for (int nt=0; nt<3; ++nt)
      bF[nt] = *reinterpret_cast<const bf16x8*>(WpT + (C0 + 32*nt + l31)*1024 + m0);
    #pragma unroll
    for (int mt=0; mt<2; ++mt)
      #pragma unroll
      for (int nt=0; nt<3; ++nt)
        acc[mt][nt] = __builtin_amdgcn_mfma_f32_32x32x16_bf16(aF[mt], bF[nt], acc[mt][nt], 0, 0, 0);
  }
  #pragma unroll
  for (int nt=0; nt<3; ++nt){
    const int c = C0 + 32*nt + l31;
    const float bb = pb[c];
    #pragma unroll
    for (int mt=0; mt<2; ++mt)
      #pragma unroll
      for (int rg=0; rg<16; ++rg){
        const int r = R0 + 32*mt + (rg&3) + 8*(rg>>2) + 4*hi;
        out[r*384 + c] = acc[mt][nt][rg] + bb;
      }
  }
}

extern "C" void kernel_launch(void* const* d_in, const int* in_sizes, int n_in,
                              void* d_out, int out_size, void* d_ws, size_t ws_size,
                              hipStream_t stream) {
  const float* x     = (const float*)d_in[0];
  const float* qkvW  = (const float*)d_in[1];
  const float* qkvB  = (const float*)d_in[2];
  const float* projW = (const float*)d_in[3];
  const float* projB = (const float*)d_in[4];
  const float* ab    = (const float*)d_in[5];

  char* ws = (char*)d_ws;
  size_t off = 0;
  short* qkbuf = (short*)(ws + off); off += (size_t)MROWS*512*2;        // 102,760,448
  short* aoutb = (short*)(ws + off); off += (size_t)MROWS*1024*2;       // 205,520,896
  short* vT    = (short*)(ws + off); off += (size_t)2048*1024*56*2;     // 234,881,024
  short* WqkT  = (short*)(ws + off); off += (size_t)512*384*2;
  short* WvT   = (short*)(ws + off); off += (size_t)1024*384*2;
  short* WpT   = (short*)(ws + off); off += (size_t)384*1024*2;
  float* bqk   = (float*)(ws + off); off += (size_t)512*4;
  float* bv    = (float*)(ws + off); off += (size_t)1024*4;
  float* bias_exp = (float*)(ws + off); off += (size_t)8*64*49*4;
  if (ws_size < off) return;  // workspace insufficient — bail (will show as mismatch)

  const int conv_total = 512*384 + 1024*384 + 384*1024 + 512 + 1024 + 8*49*49;
  k_convert<<<(conv_total + 255)/256, 256, 0, stream>>>(qkvW, qkvB, projW, ab,
                                                        WqkT, WvT, WpT, bqk, bv, bias_exp);
  k_qk_gemm<<<dim3(784, 2), 512, 0, stream>>>(x, WqkT, bqk, qkbuf);
  k_vt<<<dim3(4, 2048), 256, 0, stream>>>(x, WvT, bv, vT);
  k_attn<<<2048, 512, 0, stream>>>(qkbuf, vT, bias_exp, aoutb);
  k_proj<<<784, 512, 0, stream>>>(aoutb, WpT, projB, (float*)d_out);
}

// Round 2
// 968.598 us; speedup vs baseline: 1.4048x; 1.4048x over previous
//
#include <hip/hip_runtime.h>
#include <hip/hip_bf16.h>

using bf16x8 = short __attribute__((ext_vector_type(8)));
using f32x16 = float __attribute__((ext_vector_type(16)));

#define MROWS 100352      // 2048*49
#define SCALE_Q 0.17677669529663687f

static __device__ __forceinline__ unsigned short f2bs(float f){
  unsigned u = __builtin_bit_cast(unsigned, f);
  unsigned r = (u + 0x7FFFu + ((u >> 16) & 1u)) >> 16;   // RNE
  return (unsigned short)r;
}
static __device__ __forceinline__ unsigned packbf(float a, float b){
  return (unsigned)f2bs(a) | ((unsigned)f2bs(b) << 16);
}

// ---------------- x -> bf16 cast (each thread: 8 elems) ----------------
__global__ void k_xcast(const float* __restrict__ x, short* __restrict__ xb){
  const int i = blockIdx.x*256 + threadIdx.x;
  const float4 u0 = *reinterpret_cast<const float4*>(x + (size_t)i*8);
  const float4 u1 = *reinterpret_cast<const float4*>(x + (size_t)i*8 + 4);
  bf16x8 t;
  t[0]=(short)f2bs(u0.x); t[1]=(short)f2bs(u0.y); t[2]=(short)f2bs(u0.z); t[3]=(short)f2bs(u0.w);
  t[4]=(short)f2bs(u1.x); t[5]=(short)f2bs(u1.y); t[6]=(short)f2bs(u1.z); t[7]=(short)f2bs(u1.w);
  *reinterpret_cast<bf16x8*>(xb + (size_t)i*8) = t;
}

// ---------------- weight conversion (transposed, head-permuted, q-scaled) + bias table ----------------
// qkv col c (0..1535): c<512 -> head h=c>>6, within=c&63 (q:0-31 scaled, k:32-63), orig h*192+within
//                      c>=512 -> dv=c-512, head dv>>7, orig (dv>>7)*192 + 64 + (dv&127)
__global__ void k_convert(const float* __restrict__ qkvW, const float* __restrict__ qkvB,
                          const float* __restrict__ projW, const float* __restrict__ ab,
                          short* __restrict__ WqkvT, short* __restrict__ WpT,
                          float* __restrict__ bqkv, float* __restrict__ bias_exp){
  int i = blockIdx.x*256 + threadIdx.x;
  if (i < 1536*384){
    int c = i/384, f = i - c*384;
    int src; float sc = 1.0f;
    if (c < 512){ src = (c>>6)*192 + (c&63); if ((c&63) < 32) sc = SCALE_Q; }
    else        { int dv = c - 512; src = (dv>>7)*192 + 64 + (dv&127); }
    WqkvT[i] = (short)f2bs(qkvW[f*1536 + src] * sc);
    return;
  }
  i -= 1536*384;
  if (i < 384*1024){
    int j = i/1024, m = i - j*1024;
    WpT[i] = (short)f2bs(projW[m*384 + j]);
    return;
  }
  i -= 384*1024;
  if (i < 1536){
    int c = i; int src; float sc = 1.0f;
    if (c < 512){ src = (c>>6)*192 + (c&63); if ((c&63) < 32) sc = SCALE_Q; }
    else        { int dv = c - 512; src = (dv>>7)*192 + 64 + (dv&127); }
    bqkv[c] = qkvB[src] * sc;
    return;
  }
  i -= 1536;
  if (i < 8*64*49){
    int h = i / (64*49), rem = i - h*(64*49);
    int r = rem / 49, n = rem - r*49;
    float v = 0.0f;
    if (r < 49){
      int rh = r/7, rw = r - rh*7, ch = n/7, cw = n - ch*7;
      int dh = rh>ch?rh-ch:ch-rh, dw = rw>cw?rw-cw:cw-rw;
      v = ab[h*49 + dh*7 + dw];
    }
    bias_exp[i] = v;   // layout [(h*64 + r)*49 + n], rows 49..63 zeroed
  }
}

// ---------------- fused qkv GEMM  qkvbuf[100352][1536] = xb @ WqkvT^T + b  (bf16) ----------------
// 512 thr (8 waves, 2M x 4N), tile 128x256, grid (784, 6)
__global__ __launch_bounds__(512) void k_qkv(const short* __restrict__ xb, const short* __restrict__ WqkvT,
                                             const float* __restrict__ bqkv, short* __restrict__ qkvbuf){
  const int lane = threadIdx.x & 63, w = threadIdx.x >> 6;
  const int hi = lane >> 5, l31 = lane & 31;
  const int R0 = blockIdx.x*128 + (w>>2)*64;
  const int C0 = blockIdx.y*256 + (w&3)*64;
  f32x16 acc[2][2];
  #pragma unroll
  for (int mt=0; mt<2; ++mt)
    #pragma unroll
    for (int nt=0; nt<2; ++nt) acc[mt][nt] = (f32x16)0.0f;

  for (int ks=0; ks<24; ++ks){
    const int f0 = ks*16 + hi*8;
    bf16x8 aF[2], bF[2];
    #pragma unroll
    for (int mt=0; mt<2; ++mt)
      aF[mt] = *reinterpret_cast<const bf16x8*>(xb + (R0 + 32*mt + l31)*384 + f0);
    #pragma unroll
    for (int nt=0; nt<2; ++nt)
      bF[nt] = *reinterpret_cast<const bf16x8*>(WqkvT + (C0 + 32*nt + l31)*384 + f0);
    #pragma unroll
    for (int mt=0; mt<2; ++mt)
      #pragma unroll
      for (int nt=0; nt<2; ++nt)
        acc[mt][nt] = __builtin_amdgcn_mfma_f32_32x32x16_bf16(aF[mt], bF[nt], acc[mt][nt], 0, 0, 0);
  }
  #pragma unroll
  for (int nt=0; nt<2; ++nt){
    const int c = C0 + 32*nt + l31;
    const float bb = bqkv[c];
    #pragma unroll
    for (int mt=0; mt<2; ++mt)
      #pragma unroll
      for (int rg=0; rg<16; ++rg){
        const int r = R0 + 32*mt + (rg&3) + 8*(rg>>2) + 4*hi;
        qkvbuf[r*1536 + c] = (short)f2bs(acc[mt][nt][rg] + bb);
      }
  }
}

// ---------------- attention: block = (batch, 4 heads), 256 thr; V staged in LDS (swizzled) ----------------
// LDS layout: vlds[head][n(49)][d(136 pad)], d stored at d ^ (((n>>3)&1)<<5)  -> conflict-free u16 reads
__global__ __launch_bounds__(256) void k_attn(const short* __restrict__ qkvbuf,
                                              const float* __restrict__ bias_exp, short* __restrict__ aout){
  const int lane = threadIdx.x & 63, w = threadIdx.x >> 6;
  const int hi = lane >> 5, l31 = lane & 31;
  const int b = blockIdx.x, hg = blockIdx.y;
  const int h = hg*4 + w;

  __shared__ short vlds[4*49*136];   // 53,312 B

  // stage natural-layout V for heads hg*4..hg*4+3 (qkv cols 512 + hg*512 + [0,512))
  for (int i=0; i<13; ++i){
    const int n = i*4 + w;
    if (n < 49){
      const bf16x8 vv = *reinterpret_cast<const bf16x8*>(qkvbuf + (b*49+n)*1536 + 512 + hg*512 + lane*8);
      const int hh = lane >> 4;
      const int d0 = ((lane & 15) * 8) ^ (((n>>3)&1) << 5);
      *reinterpret_cast<bf16x8*>(&vlds[(hh*49 + n)*136 + d0]) = vv;
    }
  }
  __syncthreads();

  // K fragments (A operand of S^T = K @ Q^T)
  bf16x8 kf[2][2];
  #pragma unroll
  for (int mt=0; mt<2; ++mt){
    const int n = 32*mt + l31;
    #pragma unroll
    for (int ks=0; ks<2; ++ks)
      kf[mt][ks] = (n < 49)
        ? *reinterpret_cast<const bf16x8*>(qkvbuf + (b*49+n)*1536 + h*64 + 32 + ks*16 + hi*8)
        : (bf16x8)(short)0;
  }
  const short* vb = &vlds[w*49*136];
  const int dxbase = hi << 5;

  for (int rb=0; rb<2; ++rb){
    const int r = 32*rb + l31;
    bf16x8 qf[2];
    #pragma unroll
    for (int ks=0; ks<2; ++ks)
      qf[ks] = (r < 49)
        ? *reinterpret_cast<const bf16x8*>(qkvbuf + (b*49+r)*1536 + h*64 + ks*16 + hi*8)
        : (bf16x8)(short)0;

    f32x16 s[2];
    s[0] = (f32x16)0.0f; s[1] = (f32x16)0.0f;
    #pragma unroll
    for (int ks=0; ks<2; ++ks){
      s[0] = __builtin_amdgcn_mfma_f32_32x32x16_bf16(kf[0][ks], qf[ks], s[0], 0, 0, 0);
      s[1] = __builtin_amdgcn_mfma_f32_32x32x16_bf16(kf[1][ks], qf[ks], s[1], 0, 0, 0);
    }

    // + bias, mask, row max (row lives in lanes l and l^32); SCALE pre-folded into Wq
    float mloc = -3.0e38f;
    #pragma unroll
    for (int mt=0; mt<2; ++mt)
      #pragma unroll
      for (int rg=0; rg<16; ++rg){
        const int n = 32*mt + (rg&3) + 8*(rg>>2) + 4*hi;
        float v = s[mt][rg];
        v = (n < 49) ? v + bias_exp[(h*64 + r)*49 + n] : -1.0e30f;
        s[mt][rg] = v;
        mloc = fmaxf(mloc, v);
      }
    const float mrow = fmaxf(mloc, __shfl_xor(mloc, 32));
    float sloc = 0.0f;
    #pragma unroll
    for (int mt=0; mt<2; ++mt)
      #pragma unroll
      for (int rg=0; rg<16; ++rg){
        const float p = __expf(s[mt][rg] - mrow);
        s[mt][rg] = p; sloc += p;
      }
    const float inv = 1.0f / (sloc + __shfl_xor(sloc, 32));
    #pragma unroll
    for (int mt=0; mt<2; ++mt)
      #pragma unroll
      for (int rg=0; rg<16; ++rg) s[mt][rg] *= inv;

    // pack P into bf16 A-fragments (lane's row r, octets along n; halves swap via lane^32)
    unsigned pk[8][2];
    #pragma unroll
    for (int o=0; o<8; ++o){
      const int mt = o>>2, base = 4*(o&3);
      pk[o][0] = packbf(s[mt][base+0], s[mt][base+1]);
      pk[o][1] = packbf(s[mt][base+2], s[mt][base+3]);
    }
    bf16x8 af[4];
    #pragma unroll
    for (int ks=0; ks<4; ++ks){
      const unsigned e0 = pk[2*ks][0],   e1 = pk[2*ks][1];
      const unsigned o0 = pk[2*ks+1][0], o1 = pk[2*ks+1][1];
      const unsigned own0 = hi ? o0 : e0, own1 = hi ? o1 : e1;
      const unsigned oth0 = hi ? e0 : o0, oth1 = hi ? e1 : o1;
      const unsigned sw0 = __shfl_xor(oth0, 32), sw1 = __shfl_xor(oth1, 32);
      const unsigned lo0 = hi ? sw0 : own0, lo1 = hi ? sw1 : own1;
      const unsigned h0  = hi ? own0 : sw0, h1  = hi ? own1 : sw1;
      union { bf16x8 v; unsigned u[4]; } t;
      t.u[0]=lo0; t.u[1]=lo1; t.u[2]=h0; t.u[3]=h1;
      af[ks] = t.v;
    }

    // PV: B-fragments assembled from LDS (lane=d, 8 elems along n)
    #pragma unroll
    for (int dt=0; dt<4; ++dt){
      const int dx = (dt*32 + l31) ^ dxbase;
      f32x16 acc = (f32x16)0.0f;
      #pragma unroll
      for (int ks=0; ks<4; ++ks){
        bf16x8 t;
        if (ks < 3){
          const int nb = ks*16 + hi*8;
          #pragma unroll
          for (int j=0; j<8; ++j) t[j] = vb[(nb + j)*136 + dx];
        } else {
          #pragma unroll
          for (int j=0; j<8; ++j) t[j] = 0;
          if (hi == 0) t[0] = vb[48*136 + (dt*32 + l31)];   // n=48: swizzle bit 0
        }
        acc = __builtin_amdgcn_mfma_f32_32x32x16_bf16(af[ks], t, acc, 0, 0, 0);
      }
      #pragma unroll
      for (int rg=0; rg<16; ++rg){
        const int rr = 32*rb + (rg&3) + 8*(rg>>2) + 4*hi;
        if (rr < 49)
          aout[(b*49+rr)*1024 + h*128 + dt*32 + l31] = (short)f2bs(acc[rg]);
      }
    }
  }
}

// ---------------- proj GEMM  out[100352][384] = aout @ Wp + pb  (fp32 out) ----------------
// 512 thr (8 waves, 2M x 4N), tile 128x384, grid 784
__global__ __launch_bounds__(512) void k_proj(const short* __restrict__ aout, const short* __restrict__ WpT,
                                              const float* __restrict__ pb, float* __restrict__ out){
  const int lane = threadIdx.x & 63, w = threadIdx.x >> 6;
  const int hi = lane >> 5, l31 = lane & 31;
  const int R0 = blockIdx.x*128 + (w>>2)*64;
  const int C0 = (w&3)*96;
  f32x16 acc[2][3];
  #pragma unroll
  for (int mt=0; mt<2; ++mt)
    #pragma unroll
    for (int nt=0; nt<3; ++nt) acc[mt][nt] = (f32x16)0.0f;

  for (int ks=0; ks<64; ++ks){
    const int m0 = ks*16 + hi*8;
    bf16x8 aF[2], bF[3];
    #pragma unroll
    for (int mt=0; mt<2; ++mt)
      aF[mt] = *reinterpret_cast<const bf16x8*>(aout + (R0 + 32*mt + l31)*1024 + m0);
    #pragma unroll
    for (int nt=0; nt<3; ++nt)
      bF[nt] = *reinterpret_cast<const bf16x8*>(WpT + (C0 + 32*nt + l31)*1024 + m0);
    #pragma unroll
    for (int mt=0; mt<2; ++mt)
      #pragma unroll
      for (int nt=0; nt<3; ++nt)
        acc[mt][nt] = __builtin_amdgcn_mfma_f32_32x32x16_bf16(aF[mt], bF[nt], acc[mt][nt], 0, 0, 0);
  }
  #pragma unroll
  for (int nt=0; nt<3; ++nt){
    const int c = C0 + 32*nt + l31;
    const float bb = pb[c];
    #pragma unroll
    for (int mt=0; mt<2; ++mt)
      #pragma unroll
      for (int rg=0; rg<16; ++rg){
        const int r = R0 + 32*mt + (rg&3) + 8*(rg>>2) + 4*hi;
        out[r*384 + c] = acc[mt][nt][rg] + bb;
      }
  }
}

extern "C" void kernel_launch(void* const* d_in, const int* in_sizes, int n_in,
                              void* d_out, int out_size, void* d_ws, size_t ws_size,
                              hipStream_t stream) {
  const float* x     = (const float*)d_in[0];
  const float* qkvW  = (const float*)d_in[1];
  const float* qkvB  = (const float*)d_in[2];
  const float* projW = (const float*)d_in[3];
  const float* projB = (const float*)d_in[4];
  const float* ab    = (const float*)d_in[5];

  char* ws = (char*)d_ws;
  // region1: xb (77 MB) aliased under aoutb (205.5 MB) — xb dead before k_attn writes aoutb
  short* aoutb = (short*)ws;
  short* xb    = (short*)ws;
  size_t off = (size_t)MROWS*1024*2;
  short* qkvbuf = (short*)(ws + off); off += (size_t)MROWS*1536*2;
  short* WqkvT  = (short*)(ws + off); off += (size_t)1536*384*2;
  short* WpT    = (short*)(ws + off); off += (size_t)384*1024*2;
  float* bqkv   = (float*)(ws + off); off += (size_t)1536*4;
  float* bias_exp = (float*)(ws + off); off += (size_t)8*64*49*4;
  if (ws_size < off) return;

  const int conv_total = 1536*384 + 384*1024 + 1536 + 8*64*49;   // 1,009,664 = 3944*256
  k_convert<<<(conv_total + 255)/256, 256, 0, stream>>>(qkvW, qkvB, projW, ab,
                                                        WqkvT, WpT, bqkv, bias_exp);
  k_xcast<<<MROWS*384/8/256, 256, 0, stream>>>(x, xb);          // 18816 blocks
  k_qkv<<<dim3(784, 6), 512, 0, stream>>>(xb, WqkvT, bqkv, qkvbuf);
  k_attn<<<dim3(2048, 2), 256, 0, stream>>>(qkvbuf, bias_exp, aoutb);
  k_proj<<<784, 512, 0, stream>>>(aoutb, WpT, projB, (float*)d_out);
}

// Round 3
// 526.696 us; speedup vs baseline: 2.5835x; 1.8390x over previous
//
#include <hip/hip_runtime.h>
#include <hip/hip_bf16.h>

using bf16x8 = short __attribute__((ext_vector_type(8)));
using f32x16 = float __attribute__((ext_vector_type(16)));

#define MROWS 100352      // 2048*49
#define SCALE_Q 0.17677669529663687f

static __device__ __forceinline__ unsigned short f2bs(float f){
  unsigned u = __builtin_bit_cast(unsigned, f);
  unsigned r = (u + 0x7FFFu + ((u >> 16) & 1u)) >> 16;   // RNE
  return (unsigned short)r;
}
static __device__ __forceinline__ unsigned packbf(float a, float b){
  return (unsigned)f2bs(a) | ((unsigned)f2bs(b) << 16);
}

// ---------------- x -> bf16 cast (each thread: 8 elems) ----------------
__global__ void k_xcast(const float* __restrict__ x, short* __restrict__ xb){
  const int i = blockIdx.x*256 + threadIdx.x;
  const float4 u0 = *reinterpret_cast<const float4*>(x + (size_t)i*8);
  const float4 u1 = *reinterpret_cast<const float4*>(x + (size_t)i*8 + 4);
  bf16x8 t;
  t[0]=(short)f2bs(u0.x); t[1]=(short)f2bs(u0.y); t[2]=(short)f2bs(u0.z); t[3]=(short)f2bs(u0.w);
  t[4]=(short)f2bs(u1.x); t[5]=(short)f2bs(u1.y); t[6]=(short)f2bs(u1.z); t[7]=(short)f2bs(u1.w);
  *reinterpret_cast<bf16x8*>(xb + (size_t)i*8) = t;
}

// ---------------- weight conversion (transposed, head-permuted, q-scaled) + bias table ----------------
__global__ void k_convert(const float* __restrict__ qkvW, const float* __restrict__ qkvB,
                          const float* __restrict__ projW, const float* __restrict__ ab,
                          short* __restrict__ WqkvT, short* __restrict__ WpT,
                          float* __restrict__ bqkv, float* __restrict__ bias_exp){
  int i = blockIdx.x*256 + threadIdx.x;
  if (i < 1536*384){
    int c = i/384, f = i - c*384;
    int src; float sc = 1.0f;
    if (c < 512){ src = (c>>6)*192 + (c&63); if ((c&63) < 32) sc = SCALE_Q; }
    else        { int dv = c - 512; src = (dv>>7)*192 + 64 + (dv&127); }
    WqkvT[i] = (short)f2bs(qkvW[f*1536 + src] * sc);
    return;
  }
  i -= 1536*384;
  if (i < 384*1024){
    int j = i/1024, m = i - j*1024;
    WpT[i] = (short)f2bs(projW[m*384 + j]);
    return;
  }
  i -= 384*1024;
  if (i < 1536){
    int c = i; int src; float sc = 1.0f;
    if (c < 512){ src = (c>>6)*192 + (c&63); if ((c&63) < 32) sc = SCALE_Q; }
    else        { int dv = c - 512; src = (dv>>7)*192 + 64 + (dv&127); }
    bqkv[c] = qkvB[src] * sc;
    return;
  }
  i -= 1536;
  if (i < 8*64*49){
    int h = i / (64*49), rem = i - h*(64*49);
    int r = rem / 49, n = rem - r*49;
    float v = 0.0f;
    if (r < 49){
      int rh = r/7, rw = r - rh*7, ch = n/7, cw = n - ch*7;
      int dh = rh>ch?rh-ch:ch-rh, dw = rw>cw?rw-cw:cw-rw;
      v = ab[h*49 + dh*7 + dw];
    }
    bias_exp[i] = v;
  }
}

// ---------------- LDS-staged GEMM: C[M][ldc], tile 128x128, BK=64, 4 waves ----------------
// A [M][KTOT] bf16 row-major, Bw [N][KTOT] bf16 row-major (weights pre-transposed).
// Staging: global_load_lds width 16, LDS dest linear, XOR-swizzle (slot ^= row&7) applied on
// the per-lane GLOBAL source address; ds_read applies the same swizzle. (both-sides rule #21)
template<int KTOT, bool F32OUT>
__global__ __launch_bounds__(256) void k_gemm(const short* __restrict__ A,
                                              const short* __restrict__ Bw,
                                              const float* __restrict__ bias,
                                              void* __restrict__ Cout, int ldc){
  __shared__ short Alds[128*64];
  __shared__ short Blds[128*64];
  const int lane = threadIdx.x & 63, w = threadIdx.x >> 6;
  const int hi = lane >> 5, l31 = lane & 31;
  const int wm = w >> 1, wn = w & 1;
  const size_t R0 = (size_t)blockIdx.x*128, C0 = (size_t)blockIdx.y*128;

  f32x16 acc[2][2];
  acc[0][0]=(f32x16)0.f; acc[0][1]=(f32x16)0.f; acc[1][0]=(f32x16)0.f; acc[1][1]=(f32x16)0.f;

  const int srow = lane >> 3;                 // row-within-8 written by this lane; row&7 == srow
  const int sG   = ((lane & 7) ^ srow) * 8;   // logical k-chunk this lane must fetch (pre-swizzled src)
  const short* aG = A  + (R0 + (size_t)(w*8 + srow))*KTOT + sG;
  const short* bG = Bw + (C0 + (size_t)(w*8 + srow))*KTOT + sG;

  constexpr int NK = KTOT/64;
  for (int kt=0; kt<NK; ++kt){
    #pragma unroll
    for (int j=0; j<4; ++j){
      __builtin_amdgcn_global_load_lds(
        (const unsigned int __attribute__((address_space(1)))*)(aG + (size_t)j*32*KTOT + kt*64),
        (unsigned int __attribute__((address_space(3)))*)(&Alds[(j*32 + w*8)*64]), 16, 0, 0);
      __builtin_amdgcn_global_load_lds(
        (const unsigned int __attribute__((address_space(1)))*)(bG + (size_t)j*32*KTOT + kt*64),
        (unsigned int __attribute__((address_space(3)))*)(&Blds[(j*32 + w*8)*64]), 16, 0, 0);
    }
    __syncthreads();
    #pragma unroll
    for (int ks=0; ks<4; ++ks){
      bf16x8 aF[2], bF[2];
      #pragma unroll
      for (int mt=0; mt<2; ++mt){
        const int rA = wm*64 + mt*32 + l31;
        aF[mt] = *reinterpret_cast<const bf16x8*>(
                   (const char*)Alds + rA*128 + ((((ks<<1)|hi) ^ (rA&7))<<4));
      }
      #pragma unroll
      for (int nt=0; nt<2; ++nt){
        const int rB = wn*64 + nt*32 + l31;
        bF[nt] = *reinterpret_cast<const bf16x8*>(
                   (const char*)Blds + rB*128 + ((((ks<<1)|hi) ^ (rB&7))<<4));
      }
      #pragma unroll
      for (int mt=0; mt<2; ++mt)
        #pragma unroll
        for (int nt=0; nt<2; ++nt)
          acc[mt][nt] = __builtin_amdgcn_mfma_f32_32x32x16_bf16(aF[mt], bF[nt], acc[mt][nt], 0,0,0);
    }
    __syncthreads();
  }

  #pragma unroll
  for (int nt=0; nt<2; ++nt){
    const int c = (int)C0 + wn*64 + nt*32 + l31;
    const float bb = bias[c];
    #pragma unroll
    for (int mt=0; mt<2; ++mt){
      const size_t rbase = R0 + wm*64 + mt*32;
      #pragma unroll
      for (int rg=0; rg<16; ++rg){
        const size_t r = rbase + (rg&3) + 8*(rg>>2) + 4*hi;
        if constexpr (F32OUT) ((float*)Cout)[r*ldc + c] = acc[mt][nt][rg] + bb;
        else                  ((short*)Cout)[r*ldc + c] = (short)f2bs(acc[mt][nt][rg] + bb);
      }
    }
  }
}

// ---------------- attention: block = (batch, 4 heads), 256 thr; V staged in LDS (swizzled) ----------------
__global__ __launch_bounds__(256) void k_attn(const short* __restrict__ qkvbuf,
                                              const float* __restrict__ bias_exp, short* __restrict__ aout){
  const int lane = threadIdx.x & 63, w = threadIdx.x >> 6;
  const int hi = lane >> 5, l31 = lane & 31;
  const int b = blockIdx.x, hg = blockIdx.y;
  const int h = hg*4 + w;

  __shared__ short vlds[4*49*136];   // 53,312 B

  for (int i=0; i<13; ++i){
    const int n = i*4 + w;
    if (n < 49){
      const bf16x8 vv = *reinterpret_cast<const bf16x8*>(qkvbuf + (b*49+n)*1536 + 512 + hg*512 + lane*8);
      const int hh = lane >> 4;
      const int d0 = ((lane & 15) * 8) ^ (((n>>3)&1) << 5);
      *reinterpret_cast<bf16x8*>(&vlds[(hh*49 + n)*136 + d0]) = vv;
    }
  }
  __syncthreads();

  bf16x8 kf[2][2];
  #pragma unroll
  for (int mt=0; mt<2; ++mt){
    const int n = 32*mt + l31;
    #pragma unroll
    for (int ks=0; ks<2; ++ks)
      kf[mt][ks] = (n < 49)
        ? *reinterpret_cast<const bf16x8*>(qkvbuf + (b*49+n)*1536 + h*64 + 32 + ks*16 + hi*8)
        : (bf16x8)(short)0;
  }
  const short* vb = &vlds[w*49*136];
  const int dxbase = hi << 5;

  for (int rb=0; rb<2; ++rb){
    const int r = 32*rb + l31;
    bf16x8 qf[2];
    #pragma unroll
    for (int ks=0; ks<2; ++ks)
      qf[ks] = (r < 49)
        ? *reinterpret_cast<const bf16x8*>(qkvbuf + (b*49+r)*1536 + h*64 + ks*16 + hi*8)
        : (bf16x8)(short)0;

    f32x16 s[2];
    s[0] = (f32x16)0.0f; s[1] = (f32x16)0.0f;
    #pragma unroll
    for (int ks=0; ks<2; ++ks){
      s[0] = __builtin_amdgcn_mfma_f32_32x32x16_bf16(kf[0][ks], qf[ks], s[0], 0, 0, 0);
      s[1] = __builtin_amdgcn_mfma_f32_32x32x16_bf16(kf[1][ks], qf[ks], s[1], 0, 0, 0);
    }

    float mloc = -3.0e38f;
    #pragma unroll
    for (int mt=0; mt<2; ++mt)
      #pragma unroll
      for (int rg=0; rg<16; ++rg){
        const int n = 32*mt + (rg&3) + 8*(rg>>2) + 4*hi;
        float v = s[mt][rg];
        v = (n < 49) ? v + bias_exp[(h*64 + r)*49 + n] : -1.0e30f;
        s[mt][rg] = v;
        mloc = fmaxf(mloc, v);
      }
    const float mrow = fmaxf(mloc, __shfl_xor(mloc, 32));
    float sloc = 0.0f;
    #pragma unroll
    for (int mt=0; mt<2; ++mt)
      #pragma unroll
      for (int rg=0; rg<16; ++rg){
        const float p = __expf(s[mt][rg] - mrow);
        s[mt][rg] = p; sloc += p;
      }
    const float inv = 1.0f / (sloc + __shfl_xor(sloc, 32));
    #pragma unroll
    for (int mt=0; mt<2; ++mt)
      #pragma unroll
      for (int rg=0; rg<16; ++rg) s[mt][rg] *= inv;

    unsigned pk[8][2];
    #pragma unroll
    for (int o=0; o<8; ++o){
      const int mt = o>>2, base = 4*(o&3);
      pk[o][0] = packbf(s[mt][base+0], s[mt][base+1]);
      pk[o][1] = packbf(s[mt][base+2], s[mt][base+3]);
    }
    bf16x8 af[4];
    #pragma unroll
    for (int ks=0; ks<4; ++ks){
      const unsigned e0 = pk[2*ks][0],   e1 = pk[2*ks][1];
      const unsigned o0 = pk[2*ks+1][0], o1 = pk[2*ks+1][1];
      const unsigned own0 = hi ? o0 : e0, own1 = hi ? o1 : e1;
      const unsigned oth0 = hi ? e0 : o0, oth1 = hi ? e1 : o1;
      const unsigned sw0 = __shfl_xor(oth0, 32), sw1 = __shfl_xor(oth1, 32);
      const unsigned lo0 = hi ? sw0 : own0, lo1 = hi ? sw1 : own1;
      const unsigned h0  = hi ? own0 : sw0, h1  = hi ? own1 : sw1;
      union { bf16x8 v; unsigned u[4]; } t;
      t.u[0]=lo0; t.u[1]=lo1; t.u[2]=h0; t.u[3]=h1;
      af[ks] = t.v;
    }

    #pragma unroll
    for (int dt=0; dt<4; ++dt){
      const int dx = (dt*32 + l31) ^ dxbase;
      f32x16 acc = (f32x16)0.0f;
      #pragma unroll
      for (int ks=0; ks<4; ++ks){
        bf16x8 t;
        if (ks < 3){
          const int nb = ks*16 + hi*8;
          #pragma unroll
          for (int j=0; j<8; ++j) t[j] = vb[(nb + j)*136 + dx];
        } else {
          #pragma unroll
          for (int j=0; j<8; ++j) t[j] = 0;
          if (hi == 0) t[0] = vb[48*136 + (dt*32 + l31)];
        }
        acc = __builtin_amdgcn_mfma_f32_32x32x16_bf16(af[ks], t, acc, 0, 0, 0);
      }
      #pragma unroll
      for (int rg=0; rg<16; ++rg){
        const int rr = 32*rb + (rg&3) + 8*(rg>>2) + 4*hi;
        if (rr < 49)
          aout[(b*49+rr)*1024 + h*128 + dt*32 + l31] = (short)f2bs(acc[rg]);
      }
    }
  }
}

extern "C" void kernel_launch(void* const* d_in, const int* in_sizes, int n_in,
                              void* d_out, int out_size, void* d_ws, size_t ws_size,
                              hipStream_t stream) {
  const float* x     = (const float*)d_in[0];
  const float* qkvW  = (const float*)d_in[1];
  const float* qkvB  = (const float*)d_in[2];
  const float* projW = (const float*)d_in[3];
  const float* projB = (const float*)d_in[4];
  const float* ab    = (const float*)d_in[5];

  char* ws = (char*)d_ws;
  // xb (77 MB) aliased under aoutb (205.5 MB) — xb dead before k_attn writes aoutb
  short* aoutb = (short*)ws;
  short* xb    = (short*)ws;
  size_t off = (size_t)MROWS*1024*2;
  short* qkvbuf = (short*)(ws + off); off += (size_t)MROWS*1536*2;
  short* WqkvT  = (short*)(ws + off); off += (size_t)1536*384*2;
  short* WpT    = (short*)(ws + off); off += (size_t)384*1024*2;
  float* bqkv   = (float*)(ws + off); off += (size_t)1536*4;
  float* bias_exp = (float*)(ws + off); off += (size_t)8*64*49*4;
  if (ws_size < off) return;

  const int conv_total = 1536*384 + 384*1024 + 1536 + 8*64*49;
  k_convert<<<(conv_total + 255)/256, 256, 0, stream>>>(qkvW, qkvB, projW, ab,
                                                        WqkvT, WpT, bqkv, bias_exp);
  k_xcast<<<MROWS*384/8/256, 256, 0, stream>>>(x, xb);
  k_gemm<384,false><<<dim3(784, 12), 256, 0, stream>>>(xb, WqkvT, bqkv, qkvbuf, 1536);
  k_attn<<<dim3(2048, 2), 256, 0, stream>>>(qkvbuf, bias_exp, aoutb);
  k_gemm<1024,true><<<dim3(784, 3), 256, 0, stream>>>(aoutb, WpT, projB, d_out, 384);
}